// Round 17
// baseline (197.748 us; speedup 1.0000x reference)
//
#include <hip/hip_runtime.h>
#include <cstdint>
#include <cstddef>

// InterpAttentionKHeadsNet — round 17: r16 + epilogue restructure.
// r16 pipe budget/CU: LDS ~85us > VALU ~67 > MFMA ~43 > L2 ~37; wall 165.
// Two LDS/critical-path cuts that leave the proven layer loop untouched:
// (1) S folded into H3 epilogue: S[m] = wv8.relu(H3) computed from the fp32
//     acc ALREADY IN REGISTERS (32 fma/lane + shfl32 + Sp8[8][64] partials)
//     -> S-phase LDS re-read of H3 deleted.
// (2) Q split across ALL 8 waves: wave = (hg = w>>1 head-group, mh = w&1
//     query-pair); 2 Q-MFMA tiles/wave vs 4 on half the waves -> epilogue
//     critical path halved. Same barriers; Wq re-read 2x (L2-hot, tiny).
// Everything else byte-identical to r16 (gather readfirstlane fix, (512,8),
// 82% occupancy). Tripwire: WRITE_SIZE must stay ~156KB.

#define NLAT 256
#define KNB 16
#define QB 4
#define MROWS 64       // QB*KNB rows per block
#define ROWB 528       // 264 f16: 256 ch used + pad
#define MTSTR 16896    // 32*ROWB

typedef float    f32x4  __attribute__((ext_vector_type(4)));
typedef float    f32x16 __attribute__((ext_vector_type(16)));
typedef _Float16 f16x8  __attribute__((ext_vector_type(8)));
typedef _Float16 f16x4  __attribute__((ext_vector_type(4)));

struct Smem {
  unsigned char buf[MROWS * ROWB];  // 33,792 B in-place activations
  float Sp[4][MROWS];               // softmax head-group partials
  float Sp8[8][MROWS];              // per-wave S partials (from H3 epilogue)
  int sidx[MROWS];
  int is64;
};

// In-place layer, 8-wave: wave computes C'[32ch x 64m] via 1x2 tiles of
// 32x32x16. Wp pack: f16 elem = ks*4096 + ch*16 + (k&15).
// If wv8s != nullptr (H3): also accumulate S-partials from the fp32 acc
// (in-register, pre-f16-rounding) into Sp8[wave][m].
__device__ __forceinline__ void layer_mfma32(
    unsigned char* __restrict__ buf, const unsigned short* __restrict__ Wp,
    const float* __restrict__ bias, int lane, int wave,
    const float* __restrict__ wv8s, float* __restrict__ Sp8)
{
  const int lm32 = lane & 31, h = lane >> 5;
  const char* bp = (const char*)buf + lm32 * 528 + h * 16;
  // A-frag: ch = wave*32 + lm32 -> byte = ks*8192 + ch*32 + h*16
  const char* wbase = (const char*)Wp + (wave * 32 + lm32) * 32 + h * 16;

  f32x16 acc[2];
  acc[0] = (f32x16)(0.f);
  acc[1] = (f32x16)(0.f);

#pragma unroll
  for (int ks = 0; ks < 16; ++ks) {
    f16x8 a = *(const f16x8*)(wbase + ks * 8192);
    f16x8 b0 = *(const f16x8*)(bp + ks * 32);
    f16x8 b1 = *(const f16x8*)(bp + MTSTR + ks * 32);
    acc[0] = __builtin_amdgcn_mfma_f32_32x32x16_f16(a, b0, acc[0], 0, 0, 0);
    acc[1] = __builtin_amdgcn_mfma_f32_32x32x16_f16(a, b1, acc[1], 0, 0, 0);
  }
  __syncthreads();  // all reads done -> safe to overwrite in place
  // C layout (32x32): col m = lane&31, ch-row = j + 8q + 4h.
  float ssum0 = 0.f, ssum1 = 0.f;
#pragma unroll
  for (int q = 0; q < 4; ++q) {
    const int ch0 = wave * 32 + q * 8 + h * 4;
    const float4 bs = *(const float4*)(bias + ch0);
    const float bb[4] = {bs.x, bs.y, bs.z, bs.w};
    float wv[4] = {0.f, 0.f, 0.f, 0.f};
    if (wv8s) {
      const float4 w4 = *(const float4*)(wv8s + ch0);
      wv[0] = w4.x; wv[1] = w4.y; wv[2] = w4.z; wv[3] = w4.w;
    }
#pragma unroll
    for (int mt = 0; mt < 2; ++mt) {
      f16x4 v;
#pragma unroll
      for (int j = 0; j < 4; ++j) {
        float x = fmaxf(acc[mt][q * 4 + j] + bb[j], 0.f);
        if (wv8s) { if (mt == 0) ssum0 += wv[j] * x; else ssum1 += wv[j] * x; }
        v[j] = (_Float16)x;
      }
      *(f16x4*)((char*)buf + (mt * 32 + lm32) * 528 + ch0 * 2) = v;
    }
  }
  if (wv8s) {  // combine h-halves (same col m, other 4 ch-rows per q)
    ssum0 += __shfl_xor(ssum0, 32);
    ssum1 += __shfl_xor(ssum1, 32);
    if (h == 0) {
      Sp8[wave * MROWS + lm32] = ssum0;        // m = 0*32 + lm32
      Sp8[wave * MROWS + 32 + lm32] = ssum1;   // m = 1*32 + lm32
    }
  }
}

extern "C" __global__ __launch_bounds__(512, 8)
void interp_mfma(const float* __restrict__ pts,
                 const float* __restrict__ ptsq,
                 const void*  __restrict__ proj,
                 const unsigned short* __restrict__ L1pre,  // fp16 [B][N][256]
                 const float* __restrict__ w1rT,            // fp32 [3][256]
                 const unsigned short* __restrict__ W2p,
                 const unsigned short* __restrict__ W3p,
                 const unsigned short* __restrict__ Wqh,    // fp16 [64][256] row-major
                 const float* __restrict__ b2, const float* __restrict__ b3,
                 const float* __restrict__ bq,
                 const float* __restrict__ wv8, const float* __restrict__ c0p,
                 float* __restrict__ out,
                 int N, int NQ)
{
  __shared__ Smem sm;
  const int tid = threadIdx.x;
  const int bid = blockIdx.x;
  const int lane = tid & 63, wave = tid >> 6;   // wave 0..7
  const int lm = lane & 15, lk = lane >> 4;

  if (tid == 0) {
    const int* p = (const int*)proj;
    int z = 1;
    for (int i = 0; i < 64; ++i) z &= (p[2 * i + 1] == 0);
    sm.is64 = z;
  }
  __syncthreads();
  if (tid < MROWS) {
    long long g = (long long)bid * QB + (tid >> 4);
    long long base = g * KNB + (tid & 15);
    sm.sidx[tid] = sm.is64 ? (int)((const long long*)proj)[base]
                           : ((const int*)proj)[base];
  }
  __syncthreads();

  // ---- gather + fused L1: 8 threads/row, 32 ch each (fp32 math pre-ReLU).
  // part wave-uniform -> readfirstlane => w1rT loads are SGPR s_loads.
  {
    const int row = tid & 63;
    const int part = __builtin_amdgcn_readfirstlane(tid >> 6);   // 0..7, uniform
    const int id = sm.sidx[row];
    const long long g = (long long)bid * QB + (row >> 4);
    const int b = (int)(g / NQ);
    const int nq = (int)(g - (long long)b * NQ);
    float rel[3];
#pragma unroll
    for (int j = 0; j < 3; ++j)
      rel[j] = ptsq[((size_t)b * 3 + j) * NQ + nq]
             - pts[((size_t)b * 3 + j) * N + id];
    const _Float16* lp = (const _Float16*)L1pre + ((size_t)b * N + id) * NLAT + part * 32;
    const float* wr0 = w1rT + part * 32;
    const float* wr1 = w1rT + 256 + part * 32;
    const float* wr2 = w1rT + 512 + part * 32;
    char* dst = (char*)sm.buf + row * 528 + part * 64;
#pragma unroll
    for (int cc = 0; cc < 4; ++cc) {
      f16x8 v = *(const f16x8*)(lp + cc * 8);
      f16x8 o;
#pragma unroll
      for (int e = 0; e < 8; ++e) {
        float x = (float)v[e] + rel[0] * wr0[cc * 8 + e]
                             + rel[1] * wr1[cc * 8 + e]
                             + rel[2] * wr2[cc * 8 + e];   // scalar (SGPR) weights
        o[e] = (_Float16)fmaxf(x, 0.f);
      }
      *(f16x8*)(dst + cc * 16) = o;
    }
  }
  __syncthreads();

  layer_mfma32(sm.buf, W2p, b2, lane, wave, nullptr, nullptr);        // H2
  __syncthreads();
  layer_mfma32(sm.buf, W3p, b3, lane, wave, wv8, &sm.Sp8[0][0]);      // H3 + S
  __syncthreads();

  // ---- Q on ALL 8 waves: wave = (hg = w>>1, mh = w&1); queries 2mh, 2mh+1
  {
    const int hg = wave >> 1, mh = wave & 1;
    const char* bp16 = (const char*)sm.buf + lm * 528 + lk * 16;
    f32x4 qacc[2];
    qacc[0] = (f32x4){0.f, 0.f, 0.f, 0.f};
    qacc[1] = (f32x4){0.f, 0.f, 0.f, 0.f};
    const char* wqb = (const char*)Wqh + (hg * 16 + lm) * 512 + lk * 16;
#pragma unroll
    for (int ks = 0; ks < 8; ++ks) {
      f16x8 a = *(const f16x8*)(wqb + ks * 64);
#pragma unroll
      for (int s = 0; s < 2; ++s) {
        const int mt = 2 * mh + s;
        f16x8 bf = *(const f16x8*)(bp16 + mt * 8448 + ks * 64);
        qacc[s] = __builtin_amdgcn_mfma_f32_16x16x32_f16(a, bf, qacc[s], 0, 0, 0);
      }
    }
    // softmax over nb (= lm lanes) per head (C: col = lm, head = hg*16+lk*4+r)
    float bqv[4];
#pragma unroll
    for (int r = 0; r < 4; ++r) bqv[r] = bq[hg * 16 + lk * 4 + r];
#pragma unroll
    for (int s = 0; s < 2; ++s) {
      float sw = 0.f;
#pragma unroll
      for (int r = 0; r < 4; ++r) {
        const float qv = qacc[s][r] + bqv[r];
        float mx = qv;
#pragma unroll
        for (int msk = 1; msk < 16; msk <<= 1) mx = fmaxf(mx, __shfl_xor(mx, msk));
        const float e = __expf(qv - mx);
        float ss = e;
#pragma unroll
        for (int msk = 1; msk < 16; msk <<= 1) ss += __shfl_xor(ss, msk);
        sw += e / ss;
      }
      sw += __shfl_xor(sw, 16);   // sum over lk quarters -> this hg's 16 heads
      sw += __shfl_xor(sw, 32);
      if (lk == 0) sm.Sp[hg][(2 * mh + s) * 16 + lm] = sw;
    }
  }
  __syncthreads();

  // ---- out[q] = (mean-head att) . S; wave w (0-3) handles query w ----
  if (wave < 4) {
    const int m = wave * 16 + lm;
    const float a = (sm.Sp[0][m] + sm.Sp[1][m] + sm.Sp[2][m] + sm.Sp[3][m]) * (1.f / 64.f);
    float sv = 0.f;
#pragma unroll
    for (int w = 0; w < 8; ++w) sv += sm.Sp8[w][m];
    float val = a * sv;
#pragma unroll
    for (int msk = 1; msk < 16; msk <<= 1) val += __shfl_xor(val, msk);
    if (lane == 0) out[(long long)bid * QB + wave] = val + c0p[0];
  }
}

// ---- l1pre (fused transpose): stage fp32 latents coalesced -> LDS fp16,
// L1pre[b][n][ch] = sum_k W1[ch][k]*latent[b][k][n] + b1[ch] (no relu).
extern "C" __global__ __launch_bounds__(256, 4)
void l1pre_k(const float* __restrict__ latents,        // fp32 [B][256][N]
             const unsigned short* __restrict__ W1p,
             const float* __restrict__ b1,
             unsigned short* __restrict__ L1pre, int N)
{
  __shared__ unsigned char buf[MROWS * ROWB];
  const int tid = threadIdx.x;
  const int b = blockIdx.y, n0 = blockIdx.x * 64;
  const int lane = tid & 63, wave = tid >> 6;
  const int lm32 = lane & 31, h = lane >> 5;

  {  // stage: thread (nl = point, octets j = (tid>>6) + 4*jj) — coalesced over nl
    const int nl = tid & 63;
    const int n = n0 + nl;
    const bool ok = (n < N);
#pragma unroll
    for (int jj = 0; jj < 8; ++jj) {
      const int j = (tid >> 6) + jj * 4;   // channel octet 0..31
      f16x8 v;
#pragma unroll
      for (int e = 0; e < 8; ++e) {
        const float x = ok ? latents[((size_t)b * NLAT + j * 8 + e) * N + n] : 0.f;
        v[e] = (_Float16)x;
      }
      *(f16x8*)((char*)buf + nl * 528 + j * 16) = v;
    }
  }
  __syncthreads();

  const char* bp = (const char*)buf + lm32 * 528 + h * 16;
  const char* wbase = (const char*)W1p + (wave * 64 + lm32) * 32 + h * 16;
  f32x16 acc[2][2];
#pragma unroll
  for (int i = 0; i < 2; ++i)
#pragma unroll
    for (int j = 0; j < 2; ++j) acc[i][j] = (f32x16)(0.f);
#pragma unroll
  for (int ks = 0; ks < 16; ++ks) {
    f16x8 a[2], bb[2];
#pragma unroll
    for (int ct = 0; ct < 2; ++ct)
      a[ct] = *(const f16x8*)(wbase + ks * 8192 + ct * 1024);
#pragma unroll
    for (int mt = 0; mt < 2; ++mt)
      bb[mt] = *(const f16x8*)(bp + mt * MTSTR + ks * 32);
#pragma unroll
    for (int ct = 0; ct < 2; ++ct)
#pragma unroll
      for (int mt = 0; mt < 2; ++mt)
        acc[ct][mt] = __builtin_amdgcn_mfma_f32_32x32x16_f16(a[ct], bb[mt], acc[ct][mt], 0, 0, 0);
  }
  // C -> global: col = point mt*32+lm32, ch = wave*64+ct*32+q*8+h*4 (+bias)
#pragma unroll
  for (int ct = 0; ct < 2; ++ct) {
#pragma unroll
    for (int q = 0; q < 4; ++q) {
      const int ch0 = wave * 64 + ct * 32 + q * 8 + h * 4;
      const float4 bs = *(const float4*)(b1 + ch0);
      const float bb[4] = {bs.x, bs.y, bs.z, bs.w};
#pragma unroll
      for (int mt = 0; mt < 2; ++mt) {
        const int n = n0 + mt * 32 + lm32;
        if (n < N) {
          f16x4 v;
#pragma unroll
          for (int j = 0; j < 4; ++j)
            v[j] = (_Float16)(acc[ct][mt][q * 4 + j] + bb[j]);
          *(f16x4*)((char*)L1pre + (((size_t)b * N + n) * NLAT + ch0) * 2) = v;
        }
      }
    }
  }
}

// ---- prep: fp16 packs, w1rT, wv8, c0 (wave-parallel) ----
extern "C" __global__ void prep_w(const float* __restrict__ W1, const float* __restrict__ W2,
                                  const float* __restrict__ W3, const float* __restrict__ Wq,
                                  const float* __restrict__ Wv, const float* __restrict__ W8,
                                  const float* __restrict__ bv, const float* __restrict__ b8,
                                  unsigned short* W1p, unsigned short* W2p,
                                  unsigned short* W3p, unsigned short* Wqh,
                                  float* w1rT, float* wv8, float* c0) {
  const int t = blockIdx.x * 256 + threadIdx.x;
  union { _Float16 h; unsigned short u; } cv;
  if (t < 65536) {
    const int ch = t >> 8, k = t & 255;
    const int dst = (k >> 4) * 4096 + ch * 16 + (k & 15);  // 32x32 k-major pack
    cv.h = (_Float16)W1[(size_t)ch * 259 + k]; W1p[dst] = cv.u;
    cv.h = (_Float16)W2[t]; W2p[dst] = cv.u;
    cv.h = (_Float16)W3[t]; W3p[dst] = cv.u;
  }
  if (t < 16384) { cv.h = (_Float16)Wq[t]; Wqh[t] = cv.u; }  // row-major
  if (t < 768) {  // w1rT[j][ch] = W1[ch][256+j]
    const int j = t >> 8, ch = t & 255;
    w1rT[t] = W1[(size_t)ch * 259 + 256 + j];
  }
  if (t < 256) {
    float s = 0.f;
    for (int o = 0; o < 256; ++o) s += Wv[(size_t)o * 256 + t] * W8[o];
    wv8[t] = s;
  }
  if (t < 64) {  // c0 = b8 + W8.bv via wave reduce
    float s = 0.f;
#pragma unroll
    for (int i = 0; i < 4; ++i) s += bv[t + 64 * i] * W8[t + 64 * i];
#pragma unroll
    for (int msk = 1; msk < 64; msk <<= 1) s += __shfl_xor(s, msk);
    if (t == 0) c0[0] = s + b8[0];
  }
}

extern "C" void kernel_launch(void* const* d_in, const int* in_sizes, int n_in,
                              void* d_out, int out_size, void* d_ws, size_t ws_size,
                              hipStream_t stream) {
  (void)n_in; (void)out_size; (void)ws_size;
  const float* latents = (const float*)d_in[0];
  const float* pts     = (const float*)d_in[1];
  const float* ptsq    = (const float*)d_in[2];
  const void*  proj    = d_in[3];
  const float* W1 = (const float*)d_in[4];  const float* b1 = (const float*)d_in[5];
  const float* W2 = (const float*)d_in[6];  const float* b2 = (const float*)d_in[7];
  const float* W3 = (const float*)d_in[8];  const float* b3 = (const float*)d_in[9];
  const float* Wq = (const float*)d_in[10]; const float* bq = (const float*)d_in[11];
  const float* Wv = (const float*)d_in[12]; const float* bv = (const float*)d_in[13];
  const float* W8 = (const float*)d_in[14]; const float* b8 = (const float*)d_in[15];
  float* out = (float*)d_out;

  const int B  = 2;
  const int N  = in_sizes[1] / (3 * B);   // pts: [B,3,N]
  const int NQ = in_sizes[2] / (3 * B);   // pts_query: [B,3,NQ]

  size_t off = 0;
  auto alloc = [&](size_t bytes) -> char* {
    char* p = (char*)d_ws + off;
    off += (bytes + 255) & ~(size_t)255;
    return p;
  };
  unsigned short* W1p = (unsigned short*)alloc(65536 * 2);
  unsigned short* W2p = (unsigned short*)alloc(65536 * 2);
  unsigned short* W3p = (unsigned short*)alloc(65536 * 2);
  unsigned short* Wqh = (unsigned short*)alloc(16384 * 2);
  float* w1rT = (float*)alloc(768 * 4);
  float* wv8  = (float*)alloc(256 * 4);
  float* c0   = (float*)alloc(4);
  unsigned short* L1pre = (unsigned short*)alloc((size_t)B * N * NLAT * 2);

  hipLaunchKernelGGL(prep_w, dim3(256), dim3(256), 0, stream,
                     W1, W2, W3, Wq, Wv, W8, bv, b8, W1p, W2p, W3p, Wqh,
                     w1rT, wv8, c0);
  hipLaunchKernelGGL(l1pre_k, dim3((N + 63) / 64, B), dim3(256), 0, stream,
                     latents, W1p, b1, L1pre, N);
  const int nblocks = (B * NQ + QB - 1) / QB;   // 5000
  hipLaunchKernelGGL(interp_mfma, dim3(nblocks), dim3(512), 0, stream,
                     pts, ptsq, proj, L1pre, w1rT, W2p, W3p, Wqh,
                     b2, b3, bq, wv8, c0, out, N, NQ);
}

// Round 18
// 191.400 us; speedup vs baseline: 1.0332x; 1.0332x over previous
//
#include <hip/hip_runtime.h>
#include <cstdint>
#include <cstddef>

// InterpAttentionKHeadsNet — round 18: REVERT to r16 (best: 191.6us total,
// 165us hot). r17's S-fold+Q-split regressed (+9us): spill reappeared
// (WRITE_SIZE 156KB->10MB — epilogue state overflowed the 32 free VGPRs at
// the (512,8) cap) and the "saved" S-phase LDS reads were already running
// concurrently with Q on disjoint waves (free overlap). r16 is a sharp local
// optimum: 82% occupancy, 4 barrier domains, zero spill, exactly at the
// register knife edge. Structure summary:
//   - L1 folded into precompute (l1pre): hot kernel = gather+rank-3 rel
//     update, 2 MFMA layers (W2,W3), Q heads, softmax, S-dot, out.
//   - V-layer folded into wv8 = W8.Wv (attention sums to 1).
//   - 512 thr x 8 waves, wave = 32-ch slice; (512,8) -> 32 VGPR + 32 acc;
//     readfirstlane pins gather weights to SGPR (the r15->r16 spill fix).
//   - ROWB 528 (odd x16 -> <=4-way LDS conflicts, zero address VALU).
// Cumulative: 3893 -> 191.6us (20.3x), absmax 4.88e-4 (3x margin).

#define NLAT 256
#define KNB 16
#define QB 4
#define MROWS 64       // QB*KNB rows per block
#define ROWB 528       // 264 f16: 256 ch used + pad
#define MTSTR 16896    // 32*ROWB

typedef float    f32x4  __attribute__((ext_vector_type(4)));
typedef float    f32x16 __attribute__((ext_vector_type(16)));
typedef _Float16 f16x8  __attribute__((ext_vector_type(8)));
typedef _Float16 f16x4  __attribute__((ext_vector_type(4)));

struct Smem {
  unsigned char buf[MROWS * ROWB];  // 33,792 B in-place activations
  float Sp[4][MROWS];
  float Sv[MROWS];
  int sidx[MROWS];
  int is64;
};

// In-place layer, 8-wave: wave computes C'[32ch x 64m] via 1x2 tiles of
// 32x32x16. Wp pack: f16 elem = ks*4096 + ch*16 + (k&15).
__device__ __forceinline__ void layer_mfma32(
    unsigned char* __restrict__ buf, const unsigned short* __restrict__ Wp,
    const float* __restrict__ bias, int lane, int wave, bool relu)
{
  const int lm32 = lane & 31, h = lane >> 5;
  const char* bp = (const char*)buf + lm32 * 528 + h * 16;
  // A-frag: ch = wave*32 + lm32 -> byte = ks*8192 + ch*32 + h*16
  const char* wbase = (const char*)Wp + (wave * 32 + lm32) * 32 + h * 16;

  f32x16 acc[2];
  acc[0] = (f32x16)(0.f);
  acc[1] = (f32x16)(0.f);

#pragma unroll
  for (int ks = 0; ks < 16; ++ks) {
    f16x8 a = *(const f16x8*)(wbase + ks * 8192);
    f16x8 b0 = *(const f16x8*)(bp + ks * 32);
    f16x8 b1 = *(const f16x8*)(bp + MTSTR + ks * 32);
    acc[0] = __builtin_amdgcn_mfma_f32_32x32x16_f16(a, b0, acc[0], 0, 0, 0);
    acc[1] = __builtin_amdgcn_mfma_f32_32x32x16_f16(a, b1, acc[1], 0, 0, 0);
  }
  __syncthreads();  // all reads done -> safe to overwrite in place
  // C layout (32x32): col m = lane&31, ch-row = j + 8q + 4h.
#pragma unroll
  for (int q = 0; q < 4; ++q) {
    const int ch0 = wave * 32 + q * 8 + h * 4;
    const float4 bs = *(const float4*)(bias + ch0);
    const float bb[4] = {bs.x, bs.y, bs.z, bs.w};
#pragma unroll
    for (int mt = 0; mt < 2; ++mt) {
      f16x4 v;
#pragma unroll
      for (int j = 0; j < 4; ++j) {
        float x = acc[mt][q * 4 + j] + bb[j];
        if (relu) x = fmaxf(x, 0.f);
        v[j] = (_Float16)x;
      }
      *(f16x4*)((char*)buf + (mt * 32 + lm32) * 528 + ch0 * 2) = v;
    }
  }
}

extern "C" __global__ __launch_bounds__(512, 8)
void interp_mfma(const float* __restrict__ pts,
                 const float* __restrict__ ptsq,
                 const void*  __restrict__ proj,
                 const unsigned short* __restrict__ L1pre,  // fp16 [B][N][256]
                 const float* __restrict__ w1rT,            // fp32 [3][256]
                 const unsigned short* __restrict__ W2p,
                 const unsigned short* __restrict__ W3p,
                 const unsigned short* __restrict__ Wqh,    // fp16 [64][256] row-major
                 const float* __restrict__ b2, const float* __restrict__ b3,
                 const float* __restrict__ bq,
                 const float* __restrict__ wv8, const float* __restrict__ c0p,
                 float* __restrict__ out,
                 int N, int NQ)
{
  __shared__ Smem sm;
  const int tid = threadIdx.x;
  const int bid = blockIdx.x;
  const int lane = tid & 63, wave = tid >> 6;   // wave 0..7
  const int lm = lane & 15, lk = lane >> 4;

  if (tid == 0) {
    const int* p = (const int*)proj;
    int z = 1;
    for (int i = 0; i < 64; ++i) z &= (p[2 * i + 1] == 0);
    sm.is64 = z;
  }
  __syncthreads();
  if (tid < MROWS) {
    long long g = (long long)bid * QB + (tid >> 4);
    long long base = g * KNB + (tid & 15);
    sm.sidx[tid] = sm.is64 ? (int)((const long long*)proj)[base]
                           : ((const int*)proj)[base];
  }
  __syncthreads();

  // ---- gather + fused L1: 8 threads/row, 32 ch each (fp32 math pre-ReLU).
  // part is wave-uniform -> readfirstlane => w1rT loads become SGPR s_loads
  // (zero VGPR cost) — the r15 spill fix.
  {
    const int row = tid & 63;
    const int part = __builtin_amdgcn_readfirstlane(tid >> 6);   // 0..7, uniform
    const int id = sm.sidx[row];
    const long long g = (long long)bid * QB + (row >> 4);
    const int b = (int)(g / NQ);
    const int nq = (int)(g - (long long)b * NQ);
    float rel[3];
#pragma unroll
    for (int j = 0; j < 3; ++j)
      rel[j] = ptsq[((size_t)b * 3 + j) * NQ + nq]
             - pts[((size_t)b * 3 + j) * N + id];
    const _Float16* lp = (const _Float16*)L1pre + ((size_t)b * N + id) * NLAT + part * 32;
    const float* wr0 = w1rT + part * 32;
    const float* wr1 = w1rT + 256 + part * 32;
    const float* wr2 = w1rT + 512 + part * 32;
    char* dst = (char*)sm.buf + row * 528 + part * 64;
#pragma unroll
    for (int cc = 0; cc < 4; ++cc) {
      f16x8 v = *(const f16x8*)(lp + cc * 8);
      f16x8 o;
#pragma unroll
      for (int e = 0; e < 8; ++e) {
        float x = (float)v[e] + rel[0] * wr0[cc * 8 + e]
                             + rel[1] * wr1[cc * 8 + e]
                             + rel[2] * wr2[cc * 8 + e];   // scalar (SGPR) weights
        o[e] = (_Float16)fmaxf(x, 0.f);
      }
      *(f16x8*)(dst + cc * 16) = o;
    }
  }
  __syncthreads();

  layer_mfma32(sm.buf, W2p, b2, lane, wave, true);   // H2
  __syncthreads();
  layer_mfma32(sm.buf, W3p, b3, lane, wave, true);   // H3
  __syncthreads();

  // ---- epilogue: Q (waves 0-3) in PARALLEL with S (waves 4-7) ----
  if (wave < 4) {
    // Q heads: wave owns 16 heads x all 64 rows
    const char* bp16 = (const char*)sm.buf + lm * 528 + lk * 16;
    f32x4 qacc[4];
#pragma unroll
    for (int mt = 0; mt < 4; ++mt) qacc[mt] = (f32x4){0.f, 0.f, 0.f, 0.f};
    {
      const char* wqb = (const char*)Wqh + (wave * 16 + lm) * 512 + lk * 16;
#pragma unroll
      for (int ks = 0; ks < 8; ++ks) {
        f16x8 a = *(const f16x8*)(wqb + ks * 64);
#pragma unroll
        for (int mt = 0; mt < 4; ++mt) {
          f16x8 bf = *(const f16x8*)(bp16 + mt * 8448 + ks * 64);
          qacc[mt] = __builtin_amdgcn_mfma_f32_16x16x32_f16(a, bf, qacc[mt], 0, 0, 0);
        }
      }
    }
    // softmax over nb (= lm lanes) per head; partial head-sums -> Sp
    float bqv[4];
#pragma unroll
    for (int r = 0; r < 4; ++r) bqv[r] = bq[wave * 16 + lk * 4 + r];
#pragma unroll
    for (int mt = 0; mt < 4; ++mt) {
      float sw = 0.f;
#pragma unroll
      for (int r = 0; r < 4; ++r) {
        const float qv = qacc[mt][r] + bqv[r];
        float mx = qv;
#pragma unroll
        for (int msk = 1; msk < 16; msk <<= 1) mx = fmaxf(mx, __shfl_xor(mx, msk));
        const float e = __expf(qv - mx);
        float s = e;
#pragma unroll
        for (int msk = 1; msk < 16; msk <<= 1) s += __shfl_xor(s, msk);
        sw += e / s;
      }
      sw += __shfl_xor(sw, 16);
      sw += __shfl_xor(sw, 32);
      if (lk == 0) sm.Sp[wave][mt * 16 + lm] = sw;
    }
  } else {
    // S[row] = wv8 . H3[row] for rows (wave-4)*16 + lm
    const int row = (wave - 4) * 16 + lm;
    const char* sp = (const char*)sm.buf + row * 528 + lk * 16;
    float sacc = 0.f;
#pragma unroll
    for (int cc = 0; cc < 8; ++cc) {
      f16x8 v = *(const f16x8*)(sp + cc * 64);
      const int k0 = cc * 32 + lk * 8;
      const float4 w0 = *(const float4*)(wv8 + k0);
      const float4 w1 = *(const float4*)(wv8 + k0 + 4);
      sacc += (float)v[0] * w0.x + (float)v[1] * w0.y
            + (float)v[2] * w0.z + (float)v[3] * w0.w;
      sacc += (float)v[4] * w1.x + (float)v[5] * w1.y
            + (float)v[6] * w1.z + (float)v[7] * w1.w;
    }
    sacc += __shfl_xor(sacc, 16);
    sacc += __shfl_xor(sacc, 32);
    if (lk == 0) sm.Sv[row] = sacc;
  }
  __syncthreads();

  // ---- out[q] = sum_nb att[m]*S[m] + c0; wave w (0-3) handles q = w ----
  if (wave < 4) {
    const int m = wave * 16 + lm;
    const float a = (sm.Sp[0][m] + sm.Sp[1][m] + sm.Sp[2][m] + sm.Sp[3][m]) * (1.f / 64.f);
    float val = a * sm.Sv[m];
#pragma unroll
    for (int msk = 1; msk < 16; msk <<= 1) val += __shfl_xor(val, msk);
    if (lane == 0) out[(long long)bid * QB + wave] = val + c0p[0];
  }
}

// ---- l1pre (fused transpose): stage fp32 latents coalesced -> LDS fp16,
// L1pre[b][n][ch] = sum_k W1[ch][k]*latent[b][k][n] + b1[ch] (no relu).
extern "C" __global__ __launch_bounds__(256, 4)
void l1pre_k(const float* __restrict__ latents,        // fp32 [B][256][N]
             const unsigned short* __restrict__ W1p,
             const float* __restrict__ b1,
             unsigned short* __restrict__ L1pre, int N)
{
  __shared__ unsigned char buf[MROWS * ROWB];
  const int tid = threadIdx.x;
  const int b = blockIdx.y, n0 = blockIdx.x * 64;
  const int lane = tid & 63, wave = tid >> 6;
  const int lm32 = lane & 31, h = lane >> 5;

  {  // stage: thread (nl = point, octets j = (tid>>6) + 4*jj) — coalesced over nl
    const int nl = tid & 63;
    const int n = n0 + nl;
    const bool ok = (n < N);
#pragma unroll
    for (int jj = 0; jj < 8; ++jj) {
      const int j = (tid >> 6) + jj * 4;   // channel octet 0..31
      f16x8 v;
#pragma unroll
      for (int e = 0; e < 8; ++e) {
        const float x = ok ? latents[((size_t)b * NLAT + j * 8 + e) * N + n] : 0.f;
        v[e] = (_Float16)x;
      }
      *(f16x8*)((char*)buf + nl * 528 + j * 16) = v;
    }
  }
  __syncthreads();

  const char* bp = (const char*)buf + lm32 * 528 + h * 16;
  const char* wbase = (const char*)W1p + (wave * 64 + lm32) * 32 + h * 16;
  f32x16 acc[2][2];
#pragma unroll
  for (int i = 0; i < 2; ++i)
#pragma unroll
    for (int j = 0; j < 2; ++j) acc[i][j] = (f32x16)(0.f);
#pragma unroll
  for (int ks = 0; ks < 16; ++ks) {
    f16x8 a[2], bb[2];
#pragma unroll
    for (int ct = 0; ct < 2; ++ct)
      a[ct] = *(const f16x8*)(wbase + ks * 8192 + ct * 1024);
#pragma unroll
    for (int mt = 0; mt < 2; ++mt)
      bb[mt] = *(const f16x8*)(bp + mt * MTSTR + ks * 32);
#pragma unroll
    for (int ct = 0; ct < 2; ++ct)
#pragma unroll
      for (int mt = 0; mt < 2; ++mt)
        acc[ct][mt] = __builtin_amdgcn_mfma_f32_32x32x16_f16(a[ct], bb[mt], acc[ct][mt], 0, 0, 0);
  }
  // C -> global: col = point mt*32+lm32, ch = wave*64+ct*32+q*8+h*4 (+bias)
#pragma unroll
  for (int ct = 0; ct < 2; ++ct) {
#pragma unroll
    for (int q = 0; q < 4; ++q) {
      const int ch0 = wave * 64 + ct * 32 + q * 8 + h * 4;
      const float4 bs = *(const float4*)(b1 + ch0);
      const float bb[4] = {bs.x, bs.y, bs.z, bs.w};
#pragma unroll
      for (int mt = 0; mt < 2; ++mt) {
        const int n = n0 + mt * 32 + lm32;
        if (n < N) {
          f16x4 v;
#pragma unroll
          for (int j = 0; j < 4; ++j)
            v[j] = (_Float16)(acc[ct][mt][q * 4 + j] + bb[j]);
          *(f16x4*)((char*)L1pre + (((size_t)b * N + n) * NLAT + ch0) * 2) = v;
        }
      }
    }
  }
}

// ---- prep: fp16 packs, w1rT, wv8, c0 (wave-parallel) ----
extern "C" __global__ void prep_w(const float* __restrict__ W1, const float* __restrict__ W2,
                                  const float* __restrict__ W3, const float* __restrict__ Wq,
                                  const float* __restrict__ Wv, const float* __restrict__ W8,
                                  const float* __restrict__ bv, const float* __restrict__ b8,
                                  unsigned short* W1p, unsigned short* W2p,
                                  unsigned short* W3p, unsigned short* Wqh,
                                  float* w1rT, float* wv8, float* c0) {
  const int t = blockIdx.x * 256 + threadIdx.x;
  union { _Float16 h; unsigned short u; } cv;
  if (t < 65536) {
    const int ch = t >> 8, k = t & 255;
    const int dst = (k >> 4) * 4096 + ch * 16 + (k & 15);  // 32x32 k-major pack
    cv.h = (_Float16)W1[(size_t)ch * 259 + k]; W1p[dst] = cv.u;
    cv.h = (_Float16)W2[t]; W2p[dst] = cv.u;
    cv.h = (_Float16)W3[t]; W3p[dst] = cv.u;
  }
  if (t < 16384) { cv.h = (_Float16)Wq[t]; Wqh[t] = cv.u; }  // row-major
  if (t < 768) {  // w1rT[j][ch] = W1[ch][256+j]
    const int j = t >> 8, ch = t & 255;
    w1rT[t] = W1[(size_t)ch * 259 + 256 + j];
  }
  if (t < 256) {
    float s = 0.f;
    for (int o = 0; o < 256; ++o) s += Wv[(size_t)o * 256 + t] * W8[o];
    wv8[t] = s;
  }
  if (t < 64) {  // c0 = b8 + W8.bv via wave reduce
    float s = 0.f;
#pragma unroll
    for (int i = 0; i < 4; ++i) s += bv[t + 64 * i] * W8[t + 64 * i];
#pragma unroll
    for (int msk = 1; msk < 64; msk <<= 1) s += __shfl_xor(s, msk);
    if (t == 0) c0[0] = s + b8[0];
  }
}

extern "C" void kernel_launch(void* const* d_in, const int* in_sizes, int n_in,
                              void* d_out, int out_size, void* d_ws, size_t ws_size,
                              hipStream_t stream) {
  (void)n_in; (void)out_size; (void)ws_size;
  const float* latents = (const float*)d_in[0];
  const float* pts     = (const float*)d_in[1];
  const float* ptsq    = (const float*)d_in[2];
  const void*  proj    = d_in[3];
  const float* W1 = (const float*)d_in[4];  const float* b1 = (const float*)d_in[5];
  const float* W2 = (const float*)d_in[6];  const float* b2 = (const float*)d_in[7];
  const float* W3 = (const float*)d_in[8];  const float* b3 = (const float*)d_in[9];
  const float* Wq = (const float*)d_in[10]; const float* bq = (const float*)d_in[11];
  const float* Wv = (const float*)d_in[12]; const float* bv = (const float*)d_in[13];
  const float* W8 = (const float*)d_in[14]; const float* b8 = (const float*)d_in[15];
  float* out = (float*)d_out;

  const int B  = 2;
  const int N  = in_sizes[1] / (3 * B);   // pts: [B,3,N]
  const int NQ = in_sizes[2] / (3 * B);   // pts_query: [B,3,NQ]

  size_t off = 0;
  auto alloc = [&](size_t bytes) -> char* {
    char* p = (char*)d_ws + off;
    off += (bytes + 255) & ~(size_t)255;
    return p;
  };
  unsigned short* W1p = (unsigned short*)alloc(65536 * 2);
  unsigned short* W2p = (unsigned short*)alloc(65536 * 2);
  unsigned short* W3p = (unsigned short*)alloc(65536 * 2);
  unsigned short* Wqh = (unsigned short*)alloc(16384 * 2);
  float* w1rT = (float*)alloc(768 * 4);
  float* wv8  = (float*)alloc(256 * 4);
  float* c0   = (float*)alloc(4);
  unsigned short* L1pre = (unsigned short*)alloc((size_t)B * N * NLAT * 2);

  hipLaunchKernelGGL(prep_w, dim3(256), dim3(256), 0, stream,
                     W1, W2, W3, Wq, Wv, W8, bv, b8, W1p, W2p, W3p, Wqh,
                     w1rT, wv8, c0);
  hipLaunchKernelGGL(l1pre_k, dim3((N + 63) / 64, B), dim3(256), 0, stream,
                     latents, W1p, b1, L1pre, N);
  const int nblocks = (B * NQ + QB - 1) / QB;   // 5000
  hipLaunchKernelGGL(interp_mfma, dim3(nblocks), dim3(512), 0, stream,
                     pts, ptsq, proj, L1pre, w1rT, W2p, W3p, Wqh,
                     b2, b3, bq, wv8, c0, out, N, NQ);
}